// Round 1
// baseline (215.397 us; speedup 1.0000x reference)
//
#include <hip/hip_runtime.h>
#include <math.h>

// Problem constants (from reference): N=500, DEG=16, E=8000, B=8, T=12, H=64, F=32
#define N_NODES 500
#define DEG     16
#define E_EDGES 8000
#define BT      96      // B*T
#define H_      64
#define F_      32

__device__ __forceinline__ float sigmoidf_(float x) {
    return 1.0f / (1.0f + __expf(-x));
}

// ---------------------------------------------------------------------------
// Kernel A: per-edge hypernetwork  h = sig(sig(feat@W1+b1)@W2+b2)  -> h0,h1
// feat = [feature[src](32) | feature[dst](32) | dist(1)]
// ---------------------------------------------------------------------------
__global__ __launch_bounds__(256) void hyper_kernel(
        const float* __restrict__ feature, const float* __restrict__ dist,
        const float* __restrict__ W1, const float* __restrict__ b1,
        const float* __restrict__ W2, const float* __restrict__ b2,
        const int* __restrict__ src, const int* __restrict__ dst,
        float* __restrict__ hbuf) {
    __shared__ float sW1[65 * 16];
    __shared__ float sb1[16];
    __shared__ float sW2[32];
    __shared__ float sb2[2];
    for (int i = threadIdx.x; i < 65 * 16; i += blockDim.x) sW1[i] = W1[i];
    if (threadIdx.x < 16) sb1[threadIdx.x] = b1[threadIdx.x];
    if (threadIdx.x < 32) sW2[threadIdx.x] = W2[threadIdx.x];
    if (threadIdx.x < 2)  sb2[threadIdx.x] = b2[threadIdx.x];
    __syncthreads();

    int e = blockIdx.x * blockDim.x + threadIdx.x;
    if (e >= E_EDGES) return;
    int s = src[e], d = dst[e];
    float fs[F_], fd[F_];
    #pragma unroll
    for (int f = 0; f < F_; f++) fs[f] = feature[s * F_ + f];
    #pragma unroll
    for (int f = 0; f < F_; f++) fd[f] = feature[d * F_ + f];
    float dv = dist[e];

    float h1v[16];
    #pragma unroll
    for (int m = 0; m < 16; m++) {
        float acc = sb1[m] + dv * sW1[64 * 16 + m];
        #pragma unroll
        for (int f = 0; f < F_; f++) acc += fs[f] * sW1[f * 16 + m];
        #pragma unroll
        for (int f = 0; f < F_; f++) acc += fd[f] * sW1[(F_ + f) * 16 + m];
        h1v[m] = sigmoidf_(acc);
    }
    float o0 = sb2[0], o1 = sb2[1];
    #pragma unroll
    for (int m = 0; m < 16; m++) {
        o0 += h1v[m] * sW2[m * 2 + 0];
        o1 += h1v[m] * sW2[m * 2 + 1];
    }
    hbuf[e * 2 + 0] = sigmoidf_(o0);
    hbuf[e * 2 + 1] = sigmoidf_(o1);
}

// ---------------------------------------------------------------------------
// Kernel B: per-node GEMM [96,64] @ [64,384] producing
//   Upack[n][bt][j] = float4{ U_A, U_B, U_C, state[n,bt,j] }   (src-side terms)
//   VA/VB/VC[n][bt][j]                                          (dst-side terms)
// where U_X = s @ X[0:64,:], V_X = s @ X[64:128,:],
//   A = W3[0].reshape(128,64), B = W3[1].reshape(128,64), C = b3.reshape(128,64)
// 384 threads: chunk c = tid>>6 in 0..5, column jj = tid&63.
// ---------------------------------------------------------------------------
__global__ __launch_bounds__(384) void gemm_pack_kernel(
        const float* __restrict__ state,
        const float* __restrict__ W3, const float* __restrict__ b3,
        float* __restrict__ Upack,   // float4 view, written as floats
        float* __restrict__ VA, float* __restrict__ VB, float* __restrict__ VC) {
    int n = blockIdx.x;
    int tid = threadIdx.x;
    int c  = tid >> 6;   // 0..5
    int jj = tid & 63;

    __shared__ __align__(16) float s_tile[BT][H_];
    for (int e = tid; e < BT * H_; e += 384) {
        int bt = e >> 6, h = e & 63;
        s_tile[bt][h] = state[(bt * N_NODES + n) * H_ + h];
    }

    // weight column for this thread: 64 regs
    const float* wsrc;
    int base;
    switch (c) {
        case 0: wsrc = W3;        base = 0;    break;  // U_A
        case 1: wsrc = W3 + 8192; base = 0;    break;  // U_B
        case 2: wsrc = b3;        base = 0;    break;  // U_C
        case 3: wsrc = W3;        base = 4096; break;  // V_A (rows 64..127)
        case 4: wsrc = W3 + 8192; base = 4096; break;  // V_B
        default: wsrc = b3;       base = 4096; break;  // V_C
    }
    float wreg[64];
    #pragma unroll
    for (int h = 0; h < 64; h++) wreg[h] = wsrc[base + h * 64 + jj];

    __syncthreads();

    for (int bt = 0; bt < BT; bt++) {
        const float4* srow = (const float4*)&s_tile[bt][0];
        float acc = 0.0f;
        #pragma unroll
        for (int h4 = 0; h4 < 16; h4++) {
            float4 sv = srow[h4];   // wave-uniform address -> LDS broadcast
            acc += sv.x * wreg[4 * h4 + 0];
            acc += sv.y * wreg[4 * h4 + 1];
            acc += sv.z * wreg[4 * h4 + 2];
            acc += sv.w * wreg[4 * h4 + 3];
        }
        int idx = (n * BT + bt) * H_ + jj;
        if (c < 3) {
            Upack[idx * 4 + c] = acc;
            if (c == 0) Upack[idx * 4 + 3] = s_tile[bt][jj];
        } else if (c == 3) VA[idx] = acc;
        else if (c == 4)   VB[idx] = acc;
        else               VC[idx] = acc;
    }
}

// ---------------------------------------------------------------------------
// Kernel C: per-dst-node online segment softmax over its 16 incoming edges.
// Edges of node n are n*16 .. n*16+15 (dst = repeat(arange(N), DEG) in ref).
// One block per node, 512 threads: jj = tid&63 (H dim), bt0 = tid>>6 (0..7),
// each thread owns 12 bt values (bt = bt0 + 8*i).
// ---------------------------------------------------------------------------
__global__ __launch_bounds__(512) void combine_kernel(
        const float4* __restrict__ Upack,
        const float* __restrict__ VA, const float* __restrict__ VB,
        const float* __restrict__ VC,
        const float* __restrict__ hbuf, const int* __restrict__ src,
        const float* __restrict__ gate,
        float* __restrict__ out) {
    int n = blockIdx.x;
    int tid = threadIdx.x;
    int jj  = tid & 63;
    int bt0 = tid >> 6;

    __shared__ int   s_src[DEG];
    __shared__ float s_h0[DEG], s_h1[DEG];
    if (tid < DEG) {
        int e = n * DEG + tid;
        s_src[tid] = src[e];
        s_h0[tid]  = hbuf[e * 2 + 0];
        s_h1[tid]  = hbuf[e * 2 + 1];
    }
    __syncthreads();

    float sg = sigmoidf_(gate[0]);

    #pragma unroll 1
    for (int i = 0; i < 12; i++) {
        int bt = bt0 + 8 * i;
        int vidx = (n * BT + bt) * H_ + jj;
        float va = VA[vidx], vb = VB[vidx], vc = VC[vidx];
        float m = -3.0e38f, l = 0.0f, num = 0.0f;
        #pragma unroll
        for (int e = 0; e < DEG; e++) {
            int   se = s_src[e];
            float h0 = s_h0[e], h1 = s_h1[e];
            float4 u = Upack[(se * BT + bt) * H_ + jj];
            float a = h0 * (u.x + va) + h1 * (u.y + vb) + (u.z + vc);
            a = (a > 0.0f) ? a : 0.01f * a;           // leaky_relu 0.01
            float mn = fmaxf(m, a);
            float sc = __expf(m - mn);
            float p  = __expf(a - mn);
            l   = l * sc + p;
            num = num * sc + p * u.w;
            m = mn;
        }
        float r = fmaxf(num / l, 0.0f) * sg;
        out[(bt * N_NODES + n) * H_ + jj] = r;
    }
}

// ---------------------------------------------------------------------------
// Workspace layout (bytes):
//   [0, 64000)                hbuf  (E*2 floats)
//   [65536, +49,152,000)      Upack (N*96*64 float4)
//   [49,217,536, +12,288,000) VA
//   [61,505,536, +12,288,000) VB
//   [73,793,536, +12,288,000) VC     total ~86.1 MB
// ---------------------------------------------------------------------------
extern "C" void kernel_launch(void* const* d_in, const int* in_sizes, int n_in,
                              void* d_out, int out_size, void* d_ws, size_t ws_size,
                              hipStream_t stream) {
    const float* state   = (const float*)d_in[0];
    const float* feature = (const float*)d_in[1];
    const float* dist    = (const float*)d_in[2];
    const float* W1      = (const float*)d_in[3];
    const float* b1      = (const float*)d_in[4];
    const float* W2      = (const float*)d_in[5];
    const float* b2      = (const float*)d_in[6];
    const float* W3      = (const float*)d_in[7];
    const float* b3      = (const float*)d_in[8];
    const float* gate    = (const float*)d_in[9];
    const int*   src     = (const int*)d_in[10];
    const int*   dst     = (const int*)d_in[11];
    float* out = (float*)d_out;

    char* ws = (char*)d_ws;
    float*  hbuf  = (float*)(ws);
    float*  Upack = (float*)(ws + 65536ULL);
    float*  VA    = (float*)(ws + 49217536ULL);
    float*  VB    = (float*)(ws + 61505536ULL);
    float*  VC    = (float*)(ws + 73793536ULL);

    hipLaunchKernelGGL(hyper_kernel, dim3((E_EDGES + 255) / 256), dim3(256), 0, stream,
                       feature, dist, W1, b1, W2, b2, src, dst, hbuf);
    hipLaunchKernelGGL(gemm_pack_kernel, dim3(N_NODES), dim3(384), 0, stream,
                       state, W3, b3, Upack, VA, VB, VC);
    hipLaunchKernelGGL(combine_kernel, dim3(N_NODES), dim3(512), 0, stream,
                       (const float4*)Upack, VA, VB, VC, hbuf, src, gate, out);
}

// Round 2
// 195.707 us; speedup vs baseline: 1.1006x; 1.1006x over previous
//
#include <hip/hip_runtime.h>
#include <math.h>

// Problem constants: N=500, DEG=16, E=8000, B=8, T=12 (BT=96), H=64, F=32
#define N_NODES 500
#define DEG     16
#define E_EDGES 8000
#define BT      96
#define H_      64
#define F_      32
#define ROWS    (BT * N_NODES)   // 48000 global rows, r = bt*500 + n

__device__ __forceinline__ float sigmoidf_(float x) {
    return 1.0f / (1.0f + __expf(-x));
}

// ---------------------------------------------------------------------------
// Kernel A: per-edge hypernetwork  h = sig(sig(feat@W1+b1)@W2+b2)  -> h0,h1
// ---------------------------------------------------------------------------
__global__ __launch_bounds__(256) void hyper_kernel(
        const float* __restrict__ feature, const float* __restrict__ dist,
        const float* __restrict__ W1, const float* __restrict__ b1,
        const float* __restrict__ W2, const float* __restrict__ b2,
        const int* __restrict__ src, const int* __restrict__ dst,
        float* __restrict__ hbuf) {
    __shared__ float sW1[65 * 16];
    __shared__ float sb1[16];
    __shared__ float sW2[32];
    __shared__ float sb2[2];
    for (int i = threadIdx.x; i < 65 * 16; i += blockDim.x) sW1[i] = W1[i];
    if (threadIdx.x < 16) sb1[threadIdx.x] = b1[threadIdx.x];
    if (threadIdx.x < 32) sW2[threadIdx.x] = W2[threadIdx.x];
    if (threadIdx.x < 2)  sb2[threadIdx.x] = b2[threadIdx.x];
    __syncthreads();

    int e = blockIdx.x * blockDim.x + threadIdx.x;
    if (e >= E_EDGES) return;
    int s = src[e], d = dst[e];
    float fs[F_], fd[F_];
    #pragma unroll
    for (int f = 0; f < F_; f++) fs[f] = feature[s * F_ + f];
    #pragma unroll
    for (int f = 0; f < F_; f++) fd[f] = feature[d * F_ + f];
    float dv = dist[e];

    float h1v[16];
    #pragma unroll
    for (int m = 0; m < 16; m++) {
        float acc = sb1[m] + dv * sW1[64 * 16 + m];
        #pragma unroll
        for (int f = 0; f < F_; f++) acc += fs[f] * sW1[f * 16 + m];
        #pragma unroll
        for (int f = 0; f < F_; f++) acc += fd[f] * sW1[(F_ + f) * 16 + m];
        h1v[m] = sigmoidf_(acc);
    }
    float o0 = sb2[0], o1 = sb2[1];
    #pragma unroll
    for (int m = 0; m < 16; m++) {
        o0 += h1v[m] * sW2[m * 2 + 0];
        o1 += h1v[m] * sW2[m * 2 + 1];
    }
    hbuf[e * 2 + 0] = sigmoidf_(o0);
    hbuf[e * 2 + 1] = sigmoidf_(o1);
}

// ---------------------------------------------------------------------------
// Kernel B: flat GEMM [48000,64] @ [64,384], rows r = bt*500+n match the
// input state layout [bt][n][h] directly. Outputs (bt-major):
//   Upack[r][jj] = float4{ uA, uB, uC, state[r][jj] }
//   VA/VB/VC[r][jj] (float planes)
// A = W3[0].reshape(128,64) rows 0..63 (U) / 64..127 (V); B = W3[1]; C = b3.
// 384 threads: chunk c = tid>>6 (0..5 -> uA,uB,uC,vA,vB,vC), column jj = tid&63.
// Block handles 96 consecutive rows (500 blocks).
// ---------------------------------------------------------------------------
__global__ __launch_bounds__(384) void gemm_pack_kernel(
        const float* __restrict__ state,
        const float* __restrict__ W3, const float* __restrict__ b3,
        float* __restrict__ Upack,   // float4 plane, written as floats
        float* __restrict__ VA, float* __restrict__ VB, float* __restrict__ VC) {
    int tid = threadIdx.x;
    int c  = tid >> 6;   // 0..5
    int jj = tid & 63;
    int r0 = blockIdx.x * BT;   // 96 rows per block

    __shared__ __align__(16) float s_tile[BT][H_];   // 24 KB

    // coalesced float4 staging of 96 contiguous rows
    const float4* st4 = (const float4*)state;
    float4* ls4 = (float4*)&s_tile[0][0];
    for (int i = tid; i < BT * H_ / 4; i += 384) ls4[i] = st4[(size_t)r0 * 16 + i];

    // weight column for this thread: 64 regs
    const float* plane = (c % 3 == 0) ? W3 : (c % 3 == 1) ? (W3 + 8192) : b3;
    int rowbase = (c < 3) ? 0 : 64;
    float wreg[64];
    #pragma unroll
    for (int h = 0; h < 64; h++) wreg[h] = plane[(rowbase + h) * 64 + jj];

    __syncthreads();

    for (int rr = 0; rr < BT; rr++) {
        const float4* srow = (const float4*)&s_tile[rr][0];
        float acc = 0.0f;
        #pragma unroll
        for (int h4 = 0; h4 < 16; h4++) {
            float4 sv = srow[h4];   // wave-uniform -> LDS broadcast
            acc += sv.x * wreg[4 * h4 + 0];
            acc += sv.y * wreg[4 * h4 + 1];
            acc += sv.z * wreg[4 * h4 + 2];
            acc += sv.w * wreg[4 * h4 + 3];
        }
        size_t idx = (size_t)(r0 + rr) * H_ + jj;
        if (c < 3) {
            Upack[idx * 4 + c] = acc;
            if (c == 0) Upack[idx * 4 + 3] = s_tile[rr][jj];
        } else if (c == 3) VA[idx] = acc;
        else if (c == 4)   VB[idx] = acc;
        else               VC[idx] = acc;
    }
}

// ---------------------------------------------------------------------------
// Kernel C: segment softmax, bt-major blocking for L2 locality.
// Grid: 12000 blocks, blockIdx = g*96 + bt (g = node-group of 4), so all
// blocks sharing a bt map to the same XCD under round-robin %8 dispatch;
// the per-bt gather working set (500*64*16B = 512 KB) then lives in one L2.
// Block: 256 threads; jj = tid&63, node n = g*4 + (tid>>6).
// ---------------------------------------------------------------------------
__global__ __launch_bounds__(256) void combine_kernel(
        const float4* __restrict__ Upack,
        const float* __restrict__ VA, const float* __restrict__ VB,
        const float* __restrict__ VC,
        const float* __restrict__ hbuf, const int* __restrict__ src,
        const float* __restrict__ gate,
        float* __restrict__ out) {
    int bt = blockIdx.x % BT;
    int g  = blockIdx.x / BT;       // 0..124
    int tid = threadIdx.x;
    int jj  = tid & 63;
    int sub = tid >> 6;             // 0..3
    int n   = g * 4 + sub;
    int n0  = g * 4;

    __shared__ int   s_src[64];
    __shared__ float s_h0[64], s_h1[64];
    if (tid < 64) {
        int e = n0 * DEG + tid;     // edges of nodes n0..n0+3 are contiguous
        s_src[tid] = src[e];
        s_h0[tid]  = hbuf[e * 2 + 0];
        s_h1[tid]  = hbuf[e * 2 + 1];
    }
    __syncthreads();

    float sg = sigmoidf_(gate[0]);

    size_t vidx = ((size_t)bt * N_NODES + n) * H_ + jj;
    float va = VA[vidx], vb = VB[vidx], vc = VC[vidx];

    size_t btbase = (size_t)bt * N_NODES * H_;
    float m = -3.0e38f, l = 0.0f, num = 0.0f;
    #pragma unroll
    for (int e = 0; e < DEG; e++) {
        int ed = sub * DEG + e;
        int se = s_src[ed];
        float h0 = s_h0[ed], h1 = s_h1[ed];
        float4 u = Upack[btbase + (size_t)se * H_ + jj];
        float a = h0 * (u.x + va) + h1 * (u.y + vb) + (u.z + vc);
        a = (a > 0.0f) ? a : 0.01f * a;               // leaky_relu 0.01
        float mn = fmaxf(m, a);
        float sc = __expf(m - mn);
        float p  = __expf(a - mn);
        l   = l * sc + p;
        num = num * sc + p * u.w;
        m = mn;
    }
    float r = fmaxf(num / l, 0.0f) * sg;
    out[vidx] = r;   // out layout [bt][n][jj] == [B,T,N,H]
}

// ---------------------------------------------------------------------------
// Workspace layout (bytes):
//   [0, 64000)                hbuf  (E*2 floats)
//   [65536, +49,152,000)      Upack (48000*64 float4)
//   [49,217,536, +12,288,000) VA
//   [61,505,536, +12,288,000) VB
//   [73,793,536, +12,288,000) VC     total ~86.1 MB
// ---------------------------------------------------------------------------
extern "C" void kernel_launch(void* const* d_in, const int* in_sizes, int n_in,
                              void* d_out, int out_size, void* d_ws, size_t ws_size,
                              hipStream_t stream) {
    const float* state   = (const float*)d_in[0];
    const float* feature = (const float*)d_in[1];
    const float* dist    = (const float*)d_in[2];
    const float* W1      = (const float*)d_in[3];
    const float* b1      = (const float*)d_in[4];
    const float* W2      = (const float*)d_in[5];
    const float* b2      = (const float*)d_in[6];
    const float* W3      = (const float*)d_in[7];
    const float* b3      = (const float*)d_in[8];
    const float* gate    = (const float*)d_in[9];
    const int*   src     = (const int*)d_in[10];
    const int*   dst     = (const int*)d_in[11];
    float* out = (float*)d_out;

    char* ws = (char*)d_ws;
    float*  hbuf  = (float*)(ws);
    float*  Upack = (float*)(ws + 65536ULL);
    float*  VA    = (float*)(ws + 49217536ULL);
    float*  VB    = (float*)(ws + 61505536ULL);
    float*  VC    = (float*)(ws + 73793536ULL);

    hipLaunchKernelGGL(hyper_kernel, dim3((E_EDGES + 255) / 256), dim3(256), 0, stream,
                       feature, dist, W1, b1, W2, b2, src, dst, hbuf);
    hipLaunchKernelGGL(gemm_pack_kernel, dim3(ROWS / BT), dim3(384), 0, stream,
                       state, W3, b3, Upack, VA, VB, VC);
    hipLaunchKernelGGL(combine_kernel, dim3(125 * BT), dim3(256), 0, stream,
                       (const float4*)Upack, VA, VB, VC, hbuf, src, gate, out);
}

// Round 3
// 187.001 us; speedup vs baseline: 1.1519x; 1.0466x over previous
//
#include <hip/hip_runtime.h>
#include <hip/hip_fp16.h>
#include <math.h>

// Problem constants: N=500, DEG=16, E=8000, B=8, T=12 (BT=96), H=64, F=32
#define N_NODES 500
#define DEG     16
#define E_EDGES 8000
#define BT      96
#define H_      64
#define F_      32
#define ROWS    (BT * N_NODES)   // 48000 rows, r = bt*500 + n

__device__ __forceinline__ float sigmoidf_(float x) {
    return 1.0f / (1.0f + __expf(-x));
}

// ---------------------------------------------------------------------------
// Kernel P: transpose weight planes -> wT[c][jj][h] (6*64*64 floats)
// plane c: 0=A_U 1=B_U 2=C_U 3=A_V 4=B_V 5=C_V, A=W3[0,:8192].view(128,64),
// B=W3[1], C=b3; U rows 0..63, V rows 64..127.
// ---------------------------------------------------------------------------
__global__ __launch_bounds__(256) void wt_prep_kernel(
        const float* __restrict__ W3, const float* __restrict__ b3,
        float* __restrict__ wT) {
    int i = blockIdx.x * 256 + threadIdx.x;
    if (i >= 6 * 64 * 64) return;
    int c  = i >> 12;
    int jj = (i >> 6) & 63;
    int h  = i & 63;
    const float* plane = (c % 3 == 0) ? W3 : (c % 3 == 1) ? (W3 + 8192) : b3;
    int rowbase = (c < 3) ? 0 : 64;
    wT[i] = plane[(rowbase + h) * 64 + jj];
}

// ---------------------------------------------------------------------------
// Kernel A: per-edge hypernetwork  h = sig(sig(feat@W1+b1)@W2+b2) -> h0,h1
// ---------------------------------------------------------------------------
__global__ __launch_bounds__(256) void hyper_kernel(
        const float* __restrict__ feature, const float* __restrict__ dist,
        const float* __restrict__ W1, const float* __restrict__ b1,
        const float* __restrict__ W2, const float* __restrict__ b2,
        const int* __restrict__ src, const int* __restrict__ dst,
        float* __restrict__ hbuf) {
    __shared__ float sW1[65 * 16];
    __shared__ float sb1[16];
    __shared__ float sW2[32];
    __shared__ float sb2[2];
    for (int i = threadIdx.x; i < 65 * 16; i += blockDim.x) sW1[i] = W1[i];
    if (threadIdx.x < 16) sb1[threadIdx.x] = b1[threadIdx.x];
    if (threadIdx.x < 32) sW2[threadIdx.x] = W2[threadIdx.x];
    if (threadIdx.x < 2)  sb2[threadIdx.x] = b2[threadIdx.x];
    __syncthreads();

    int e = blockIdx.x * blockDim.x + threadIdx.x;
    if (e >= E_EDGES) return;
    int s = src[e], d = dst[e];
    float fs[F_], fd[F_];
    #pragma unroll
    for (int f = 0; f < F_; f++) fs[f] = feature[s * F_ + f];
    #pragma unroll
    for (int f = 0; f < F_; f++) fd[f] = feature[d * F_ + f];
    float dv = dist[e];

    float h1v[16];
    #pragma unroll
    for (int m = 0; m < 16; m++) {
        float acc = sb1[m] + dv * sW1[64 * 16 + m];
        #pragma unroll
        for (int f = 0; f < F_; f++) acc += fs[f] * sW1[f * 16 + m];
        #pragma unroll
        for (int f = 0; f < F_; f++) acc += fd[f] * sW1[(F_ + f) * 16 + m];
        h1v[m] = sigmoidf_(acc);
    }
    float o0 = sb2[0], o1 = sb2[1];
    #pragma unroll
    for (int m = 0; m < 16; m++) {
        o0 += h1v[m] * sW2[m * 2 + 0];
        o1 += h1v[m] * sW2[m * 2 + 1];
    }
    hbuf[e * 2 + 0] = sigmoidf_(o0);
    hbuf[e * 2 + 1] = sigmoidf_(o1);
}

// ---------------------------------------------------------------------------
// Kernel B: flat GEMM [48000,64] @ [64,384], fp16 packed outputs (bt-major):
//   UpackH[r][jj][0..3] = half{ uA, uB, uC, state[r][jj] }
//   VpackH[r][jj][0..3] = half{ vA, vB, vC, (unused) }
// 384 threads: c = tid>>6 (plane), jj = tid&63 (column). 96 rows per block.
// __launch_bounds__(384,1): let the allocator keep the 64-float weight
// column in VGPRs (R2's (384) default chose 40 VGPRs and re-loaded weights
// from memory every row -> 64 us).
// ---------------------------------------------------------------------------
__global__ __launch_bounds__(384, 1) void gemm_pack_kernel(
        const float* __restrict__ state,
        const float* __restrict__ wT,
        __half* __restrict__ UpackH, __half* __restrict__ VpackH) {
    int tid = threadIdx.x;
    int c  = tid >> 6;   // 0..5
    int jj = tid & 63;
    int r0 = blockIdx.x * BT;

    __shared__ __align__(16) float s_tile[BT][H_];   // 24 KB

    const float4* st4 = (const float4*)state;
    float4* ls4 = (float4*)&s_tile[0][0];
    for (int i = tid; i < BT * H_ / 4; i += 384) ls4[i] = st4[(size_t)r0 * 16 + i];

    // weight column: 16 contiguous float4 (64 VGPRs), from transposed buffer
    const float4* wt4 = (const float4*)(wT + (c * 64 + jj) * 64);
    float4 w4[16];
    #pragma unroll
    for (int k = 0; k < 16; k++) w4[k] = wt4[k];

    __syncthreads();

    __half* outp = (c < 3) ? UpackH : VpackH;
    int slot = (c < 3) ? c : (c - 3);

    for (int rr = 0; rr < BT; rr++) {
        const float4* srow = (const float4*)&s_tile[rr][0];
        float acc = 0.0f;
        #pragma unroll
        for (int h4 = 0; h4 < 16; h4++) {
            float4 sv = srow[h4];   // wave-uniform -> LDS broadcast
            acc += sv.x * w4[h4].x;
            acc += sv.y * w4[h4].y;
            acc += sv.z * w4[h4].z;
            acc += sv.w * w4[h4].w;
        }
        size_t idx = ((size_t)(r0 + rr) * H_ + jj) * 4;
        outp[idx + slot] = __float2half(acc);
        if (c == 0) outp[idx + 3] = __float2half(s_tile[rr][jj]);
    }
}

// ---------------------------------------------------------------------------
// Kernel C: segment softmax, bt-major blocking for L2 locality.
// Grid: blockIdx = g*96 + bt (g = 4-node group) -> blocks sharing a bt land
// on one XCD under round-robin dispatch; per-bt gather set = 500*64*8B
// = 256 KB, L2-resident. 256 threads: jj = tid&63, n = g*4 + (tid>>6).
// ---------------------------------------------------------------------------
__global__ __launch_bounds__(256) void combine_kernel(
        const float2* __restrict__ Upack,   // half4 as float2
        const float2* __restrict__ Vpack,
        const float* __restrict__ hbuf, const int* __restrict__ src,
        const float* __restrict__ gate,
        float* __restrict__ out) {
    int bt = blockIdx.x % BT;
    int g  = blockIdx.x / BT;       // 0..124
    int tid = threadIdx.x;
    int jj  = tid & 63;
    int sub = tid >> 6;             // 0..3
    int n   = g * 4 + sub;
    int n0  = g * 4;

    __shared__ int   s_src[64];
    __shared__ float s_h0[64], s_h1[64];
    if (tid < 64) {
        int e = n0 * DEG + tid;     // edges of nodes n0..n0+3 contiguous
        s_src[tid] = src[e];
        s_h0[tid]  = hbuf[e * 2 + 0];
        s_h1[tid]  = hbuf[e * 2 + 1];
    }
    __syncthreads();

    float sg = sigmoidf_(gate[0]);

    size_t vidx = ((size_t)bt * N_NODES + n) * H_ + jj;
    float2 vraw = Vpack[vidx];
    float2 v01 = __half22float2(*(const __half2*)&vraw.x);
    float2 v23 = __half22float2(*(const __half2*)&vraw.y);
    float va = v01.x, vb = v01.y, vc = v23.x;

    size_t btbase = (size_t)bt * N_NODES * H_;
    float m = -3.0e38f, l = 0.0f, num = 0.0f;
    #pragma unroll
    for (int e = 0; e < DEG; e++) {
        int ed = sub * DEG + e;
        int se = s_src[ed];
        float h0 = s_h0[ed], h1 = s_h1[ed];
        float2 uraw = Upack[btbase + (size_t)se * H_ + jj];
        float2 u01 = __half22float2(*(const __half2*)&uraw.x);
        float2 u23 = __half22float2(*(const __half2*)&uraw.y);
        float a = h0 * (u01.x + va) + h1 * (u01.y + vb) + (u23.x + vc);
        a = (a > 0.0f) ? a : 0.01f * a;               // leaky_relu 0.01
        float mn = fmaxf(m, a);
        float sc = __expf(m - mn);
        float p  = __expf(a - mn);
        l   = l * sc + p;
        num = num * sc + p * u23.y;
        m = mn;
    }
    float r = fmaxf(num / l, 0.0f) * sg;
    out[vidx] = r;   // [bt][n][jj] == [B,T,N,H]
}

// ---------------------------------------------------------------------------
// Workspace layout (bytes):
//   [0, 64000)                  hbuf   (E*2 floats)
//   [131072, +98304)            wT     (6*64*64 floats)
//   [262144, +24576000)         UpackH (48000*64 half4)
//   [25165824, +24576000)       VpackH            total ~47.5 MB
// ---------------------------------------------------------------------------
extern "C" void kernel_launch(void* const* d_in, const int* in_sizes, int n_in,
                              void* d_out, int out_size, void* d_ws, size_t ws_size,
                              hipStream_t stream) {
    const float* state   = (const float*)d_in[0];
    const float* feature = (const float*)d_in[1];
    const float* dist    = (const float*)d_in[2];
    const float* W1      = (const float*)d_in[3];
    const float* b1      = (const float*)d_in[4];
    const float* W2      = (const float*)d_in[5];
    const float* b2      = (const float*)d_in[6];
    const float* W3      = (const float*)d_in[7];
    const float* b3      = (const float*)d_in[8];
    const float* gate    = (const float*)d_in[9];
    const int*   src     = (const int*)d_in[10];
    const int*   dst     = (const int*)d_in[11];
    float* out = (float*)d_out;

    char* ws = (char*)d_ws;
    float*  hbuf   = (float*)(ws);
    float*  wT     = (float*)(ws + 131072ULL);
    __half* UpackH = (__half*)(ws + 262144ULL);
    __half* VpackH = (__half*)(ws + 25165824ULL);

    hipLaunchKernelGGL(wt_prep_kernel, dim3((6 * 64 * 64 + 255) / 256), dim3(256), 0, stream,
                       W3, b3, wT);
    hipLaunchKernelGGL(hyper_kernel, dim3((E_EDGES + 255) / 256), dim3(256), 0, stream,
                       feature, dist, W1, b1, W2, b2, src, dst, hbuf);
    hipLaunchKernelGGL(gemm_pack_kernel, dim3(ROWS / BT), dim3(384), 0, stream,
                       state, wT, UpackH, VpackH);
    hipLaunchKernelGGL(combine_kernel, dim3(125 * BT), dim3(256), 0, stream,
                       (const float2*)UpackH, (const float2*)VpackH, hbuf, src, gate, out);
}